// Round 7
// baseline (139.005 us; speedup 1.0000x reference)
//
#include <hip/hip_runtime.h>

typedef _Float16 half8 __attribute__((ext_vector_type(8)));
typedef float floatx4 __attribute__((ext_vector_type(4)));

#define IN_DIM 256
#define OUT_DIM 256
#define ROWSTR_I 264   // int32 row stride in LDS: 1056B, 16B-aligned, mirrors R2's measured-0-conflict geometry

// Quantize weight -> f16 in MFMA-A-fragment-permuted order:
//   perm[((ct*8 + ks)*64 + lane)*8 + e] = rne(W[ct*16 + (lane&15)][ks*32 + (lane>>4)*8 + e] * 100)
// Each gemm A-frag load is one fully-coalesced 16B/lane dwordx4 from the
// L1/L2-hot 128KB buffer. Also quantizes bias and writes the scalar output.
__global__ void quant_kernel(const float* __restrict__ w,
                             const float* __restrict__ bias,
                             const float* __restrict__ in_scale,
                             _Float16* __restrict__ wqp,
                             float* __restrict__ bq,
                             float* __restrict__ out_scalar) {
    int t = blockIdx.x * blockDim.x + threadIdx.x;
    if (t < (OUT_DIM * IN_DIM) / 8) {
        int lane = t & 63;
        int ks   = (t >> 6) & 7;
        int ct   = t >> 9;
        int row  = ct * 16 + (lane & 15);
        int k0   = ks * 32 + (lane >> 4) * 8;
        const float* src = w + row * IN_DIM + k0;
        half8 h;
#pragma unroll
        for (int e = 0; e < 8; ++e)
            h[e] = (_Float16)rintf(src[e] * 100.0f); // jnp.round = round-half-even
        *((half8*)wqp + t) = h;
    }
    if (t < OUT_DIM) {
        float s2 = in_scale[0] * 100.0f;
        bq[t] = rintf(bias[t] * s2);
    }
    if (t == 0 && out_scalar != nullptr)
        out_scalar[0] = in_scale[0] * 100.0f;
}

// async 16B/lane global->LDS DMA; dest = wave-uniform base + lane*16
__device__ __forceinline__ void gl_lds16(const int* g, int* lds_row_base) {
    __builtin_amdgcn_global_load_lds(
        (const __attribute__((address_space(1))) void*)g,
        (__attribute__((address_space(3))) void*)lds_row_base,
        16, 0, 0);
}

__device__ __forceinline__ half8 cvt_frag(const int* __restrict__ rowp, int kb) {
    int4 lo = *(const int4*)(rowp + kb);       // ds_read_b128
    int4 hi = *(const int4*)(rowp + kb + 4);   // ds_read_b128
    half8 b;
    b[0] = (_Float16)lo.x; b[1] = (_Float16)lo.y;
    b[2] = (_Float16)lo.z; b[3] = (_Float16)lo.w;
    b[4] = (_Float16)hi.x; b[5] = (_Float16)hi.y;
    b[6] = (_Float16)hi.z; b[7] = (_Float16)hi.w;
    return b;
}

// Compute 4 col-tiles x 2 row-tiles over one 32-row int buffer (full K).
__device__ __forceinline__ void pass_compute(const int* __restrict__ buf,
                                             const half8* __restrict__ wbase,
                                             int wave, int lane, int m16, int quad,
                                             floatx4 (&acc)[4][2]) {
#pragma unroll
    for (int ks = 0; ks < 8; ++ks) {
        half8 afr[4];
#pragma unroll
        for (int i = 0; i < 4; ++i)            // W: coalesced, L1/L2-hot
            afr[i] = wbase[((wave * 4 + i) * 8 + ks) * 64 + lane];
        const int kb = ks * 32 + quad * 8;
        half8 bfr[2];
#pragma unroll
        for (int j = 0; j < 2; ++j)
            bfr[j] = cvt_frag(buf + (j * 16 + m16) * ROWSTR_I, kb);
#pragma unroll
        for (int i = 0; i < 4; ++i)
#pragma unroll
            for (int j = 0; j < 2; ++j)
                acc[i][j] = __builtin_amdgcn_mfma_f32_16x16x32_f16(afr[i], bfr[j], acc[i][j], 0, 0, 0);
    }
}

__device__ __forceinline__ void pass_store(float* __restrict__ out, size_t row0,
                                           const float* __restrict__ bq,
                                           int wave, int m16, int quad,
                                           floatx4 (&acc)[4][2]) {
#pragma unroll
    for (int i = 0; i < 4; ++i) {
        int col = wave * 64 + i * 16 + quad * 4;
        floatx4 bv = *(const floatx4*)(bq + col);
#pragma unroll
        for (int j = 0; j < 2; ++j) {
            size_t row = row0 + j * 16 + m16;
            *(floatx4*)(out + row * OUT_DIM + col) = acc[i][j] + bv;
        }
    }
}

// 64-row x 256-col tile per block, split into two 32-row passes.
// Pipeline: DMA rows 0-31 | barrier | DMA rows 32-63 (in flight) + compute pass A
// | barrier (drains DMA-B under cover) | store A (fire-and-forget) + compute pass B
// | store B.  DMA intrinsics can't be sunk by the compiler -> guaranteed MLP.
__global__ __launch_bounds__(256, 2) void gemm_kernel(const int* __restrict__ cx,
                                                      const _Float16* __restrict__ wqp,
                                                      const float* __restrict__ bq,
                                                      float* __restrict__ out) {
    __shared__ int bufA[32 * ROWSTR_I];   // 33.8 KB
    __shared__ int bufB[32 * ROWSTR_I];   // 33.8 KB  (total 67.6 KB -> 2 blocks/CU)

    const int t    = threadIdx.x;
    const int wave = t >> 6;
    const int lane = t & 63;
    const int m16  = lane & 15;
    const int quad = lane >> 4;

    const size_t m0 = (size_t)blockIdx.x * 64;
    const half8* wbase = (const half8*)wqp;

    // ---- DMA rows 0..31 (wave stages rows wave*8 .. wave*8+7; 1KB per DMA) ----
    {
        const int* g = cx + (m0 + wave * 8) * IN_DIM + lane * 4;
#pragma unroll
        for (int i = 0; i < 8; ++i)
            gl_lds16(g + i * IN_DIM, &bufA[(wave * 8 + i) * ROWSTR_I]);
    }
    __syncthreads();   // bufA ready

    // ---- DMA rows 32..63 (stays in flight under pass-A compute) ----
    {
        const int* g = cx + (m0 + 32 + wave * 8) * IN_DIM + lane * 4;
#pragma unroll
        for (int i = 0; i < 8; ++i)
            gl_lds16(g + i * IN_DIM, &bufB[(wave * 8 + i) * ROWSTR_I]);
    }

    // ---- pass A: rows 0..31, full K ----
    floatx4 accA[4][2] = {};
    pass_compute(bufA, wbase, wave, lane, m16, quad, accA);

    __syncthreads();   // bufB ready (drain largely covered by pass-A compute)

    // ---- store A (independent, overlaps pass-B compute) then pass B ----
    pass_store(out, m0, bq, wave, m16, quad, accA);

    floatx4 accB[4][2] = {};
    pass_compute(bufB, wbase, wave, lane, m16, quad, accB);
    pass_store(out, m0 + 32, bq, wave, m16, quad, accB);
}

extern "C" void kernel_launch(void* const* d_in, const int* in_sizes, int n_in,
                              void* d_out, int out_size, void* d_ws, size_t ws_size,
                              hipStream_t stream) {
    const int*   cx       = (const int*)d_in[0];
    const float* w        = (const float*)d_in[1];
    const float* bias     = (const float*)d_in[2];
    const float* in_scale = (const float*)d_in[3];
    float* out = (float*)d_out;

    _Float16* wqp = (_Float16*)d_ws;                              // 128 KB, permuted
    float*    bq  = (float*)((char*)d_ws + OUT_DIM * IN_DIM * 2); // 1 KB

    const int rows = in_sizes[0] / IN_DIM;          // 65536
    const size_t gemm_elems = (size_t)rows * OUT_DIM;
    float* out_scalar = ((size_t)out_size > gemm_elems) ? (out + gemm_elems) : nullptr;

    quant_kernel<<<32, 256, 0, stream>>>(w, bias, in_scale, wqp, bq, out_scalar);
    gemm_kernel<<<rows / 64, 256, 0, stream>>>(cx, wqp, bq, out);
}